// Round 11
// baseline (503.984 us; speedup 1.0000x reference)
//
#include <hip/hip_runtime.h>
#include <stdint.h>

// LiquidStateMachine on MI355X — round 11.
// r10 retrospect: amdgpu_waves_per_eu(4,4) was IGNORED (VGPR_Count stayed
// 64, WRITE_SIZE 53MB = ~40MB scratch spill) -> the r9/r10 pipeline theory
// has never run spill-free. r11 = r10 verbatim with the documented budget
// mechanism: __launch_bounds__(1024, 4) — 2nd arg = min waves/EU; 4
// waves/EU = our exact 1-block/CU occupancy -> VGPR cap 512/4 = 128.
// Inner-loop demand ~108 regs (xr 24 + 2 gather sets 32 + 2 weight sets
// 16 + rec 8 + c/v 16 + temps) fits with slack.
// Pipeline: index stream preloaded to registers (constant across steps);
// per chunk k: issue k+1 weights (L2, longest pole) + k+1 gathers (addrs
// from regs) while consuming chunk k. Spike records u8 x 8 rows @ 8k
// (b64 gathers). Weights EXACT fp32 (r2: rounding flips spikes).
//
// d_ws layout (bytes):
//   0      PERM[512]  sorted-rank -> column
//   2048   RANK[512]  column -> sorted rank
//   4096   CNT[512]   nnz per column          (zeroed via hipMemsetAsync)
//   8192   CNTW[8]    per-group padded trip count (multiple of 16)
//   8256   IBASE[8]   per-group byte base into IDX region
//   8320   WBASE[8]   per-group byte base into WT region
//   16384  IDX        u16 spike-offset (8k):
//                     byte = ib + (j>>3)*1024 + ls*16 + (j&7)*2
//   81920  WT         f32 w: byte = wb + (j>>3)*2048 + ls*32 + (j&7)*4

#define N_NEU 512
#define B_ROWS 2048
#define D_IN 256
#define R_PB 8
#define NBLK (B_ROWS / R_PB)   // 256 blocks x 1024 threads = 1 block/CU

#define WS_PERM    0
#define WS_RANK    2048
#define WS_CNT     4096
#define WS_CNTW    8192
#define WS_IBASE   8256
#define WS_WBASE   8320
#define WS_IDX     16384
#define WS_WT      81920

// spike record: 8 bytes (8 rows x u8 0/1) at natural offset 8k
#define SPK_OFF(k)  ((k) << 3)
#define SPK_REGION  4096       // 512 neurons x 8 B

// ---------------------------------------------------------------- prep A
__global__ __launch_bounds__(256) void lsm_count(
    const float* __restrict__ W, uint32_t* __restrict__ ws)
{
    int t  = threadIdx.x;
    int k0 = blockIdx.x * 4;
    int c0 = 0, c1 = 0;
    #pragma unroll
    for (int kk = 0; kk < 4; ++kk) {
        const float* row = W + (size_t)(k0 + kk) * N_NEU;
        c0 += (row[t]       != 0.0f) ? 1 : 0;
        c1 += (row[t + 256] != 0.0f) ? 1 : 0;
    }
    if (c0) atomicAdd(&ws[(WS_CNT >> 2) + t],       (uint32_t)c0);
    if (c1) atomicAdd(&ws[(WS_CNT >> 2) + t + 256], (uint32_t)c1);
}

// ---------------------------------------------------------------- prep B
__global__ __launch_bounds__(512) void lsm_sort(uint32_t* __restrict__ ws)
{
    __shared__ int hist[N_NEU + 1];
    __shared__ int csort[N_NEU];
    __shared__ int gcw[8];

    int t = threadIdx.x;
    int creal = (int)ws[(WS_CNT >> 2) + t];
    for (int i = t; i < N_NEU + 1; i += 512) hist[i] = 0;
    __syncthreads();
    atomicAdd(&hist[creal], 1);
    __syncthreads();
    if (t == 0) {
        int acc = 0;
        for (int v = 0; v <= N_NEU; ++v) { int h = hist[v]; hist[v] = acc; acc += h; }
    }
    __syncthreads();
    int rank = atomicAdd(&hist[creal], 1);
    ws[(WS_PERM >> 2) + rank] = (uint32_t)t;
    ws[(WS_RANK >> 2) + t]    = (uint32_t)rank;
    csort[rank] = creal;
    __syncthreads();
    if (t < 8) {
        int cw = csort[t * 64 + 63];         // ascending -> group max is last
        cw = (cw + 15) & ~15;                // pad to multiple of 16
        gcw[t] = cw;
        ws[(WS_CNTW >> 2) + t] = (uint32_t)cw;
    }
    __syncthreads();
    if (t == 0) {
        int ai = 0, aw = 0;
        for (int g = 0; g < 8; ++g) {
            ws[(WS_IBASE >> 2) + g] = (uint32_t)ai;
            ws[(WS_WBASE >> 2) + g] = (uint32_t)aw;
            ai += gcw[g] * 64 * 2;           // bytes (u16 per entry)
            aw += gcw[g] * 64 * 4;           // bytes (f32 per entry)
        }
    }
    __syncthreads();
    // pad tail slots of this thread's column
    int wg = rank >> 6, ls = rank & 63;
    int cw = gcw[wg];
    uint32_t ib = ws[(WS_IBASE >> 2) + wg];
    uint32_t wb = ws[(WS_WBASE >> 2) + wg];
    char* base = (char*)ws;
    for (int j = creal; j < cw; ++j) {
        *(unsigned short*)(base + WS_IDX + ib + (j >> 3) * 1024 + ls * 16 + (j & 7) * 2) = 0;
        *(float*)(base + WS_WT + wb + (j >> 3) * 2048 + ls * 32 + (j & 7) * 4) = 0.0f;
    }
}

// ---------------------------------------------------------------- prep C
__global__ __launch_bounds__(64) void lsm_fill(
    const float* __restrict__ W, uint32_t* __restrict__ ws)
{
    int c    = blockIdx.x;
    int lane = threadIdx.x;
    char* base = (char*)ws;
    uint32_t rank = ws[(WS_RANK >> 2) + c];
    int wg = (int)(rank >> 6), ls = (int)(rank & 63);
    uint32_t ib = ws[(WS_IBASE >> 2) + wg];
    uint32_t wb = ws[(WS_WBASE >> 2) + wg];

    __shared__ int ctr;
    if (lane == 0) ctr = 0;
    __syncthreads();

    for (int k = lane; k < N_NEU; k += 64) {
        float wv = W[(size_t)k * N_NEU + c];
        if (wv != 0.0f) {
            int j = atomicAdd(&ctr, 1);      // order within column irrelevant
            *(unsigned short*)(base + WS_IDX + ib + (j >> 3) * 1024 + ls * 16 + (j & 7) * 2)
                = (unsigned short)SPK_OFF(k);
            *(float*)(base + WS_WT + wb + (j >> 3) * 2048 + ls * 32 + (j & 7) * 4) = wv;
        }
    }
}

// -------- spill-proof pipeline macros (all scalars, no arrays/fns) --------
#define GATH(P, X) \
    P##0 = *(const uint2*)(smem + ((X).x & 0xffffu)); \
    P##1 = *(const uint2*)(smem + ((X).x >> 16));     \
    P##2 = *(const uint2*)(smem + ((X).y & 0xffffu)); \
    P##3 = *(const uint2*)(smem + ((X).y >> 16));     \
    P##4 = *(const uint2*)(smem + ((X).z & 0xffffu)); \
    P##5 = *(const uint2*)(smem + ((X).z >> 16));     \
    P##6 = *(const uint2*)(smem + ((X).w & 0xffffu)); \
    P##7 = *(const uint2*)(smem + ((X).w >> 16));

// one entry: weight W times 8 rows' u8 spikes ((dw>>8j)&0xff -> v_cvt_f32_ubyteN)
#define C1(S, W) \
    rec0 = fmaf((W), (float)((S).x & 0xffu),         rec0); \
    rec1 = fmaf((W), (float)(((S).x >> 8) & 0xffu),  rec1); \
    rec2 = fmaf((W), (float)(((S).x >> 16) & 0xffu), rec2); \
    rec3 = fmaf((W), (float)((S).x >> 24),           rec3); \
    rec4 = fmaf((W), (float)((S).y & 0xffu),         rec4); \
    rec5 = fmaf((W), (float)(((S).y >> 8) & 0xffu),  rec5); \
    rec6 = fmaf((W), (float)(((S).y >> 16) & 0xffu), rec6); \
    rec7 = fmaf((W), (float)((S).y >> 24),           rec7);

#define CONS(P, WA, WB) \
    C1(P##0, (WA).x) C1(P##1, (WA).y) C1(P##2, (WA).z) C1(P##3, (WA).w) \
    C1(P##4, (WB).x) C1(P##5, (WB).y) C1(P##6, (WB).z) C1(P##7, (WB).w)

#define LDW(WA, WB, K) \
    WA = ((const float4*)(wp0 + (K) * 4096))[0]; \
    WB = ((const float4*)(wp0 + (K) * 4096))[1];

// ---------------------------------------------------------------- main
// LDS map:
//   [0,4096)        spk  : u8 [8 rows] per neuron, 8 B records at 8k
//   [4096,20480)    recx : float[512 cols][8] (half-1 partial rec)
//                   rl   : overlay at 4096, rates staging [8][256] (pre-loop)
//   [20480,36864)   Ibuf : float[512 cols][8] input current
//   [36864,53248)   SSbuf: float[512 cols][8] spike-count accum
__global__ __launch_bounds__(1024, 4)   // min 4 waves/EU -> VGPR budget 128
void lsm_main(
    const float* __restrict__ rates, const float* __restrict__ inW,
    const float* __restrict__ vin,   const float* __restrict__ cin,
    const int* __restrict__ nsteps_p,
    const uint32_t* __restrict__ ws, float* __restrict__ out)
{
    __shared__ __align__(16) unsigned char smem[SPK_REGION + 3 * 16384];
    float* recx  = (float*)(smem + SPK_REGION);
    float* rl    = (float*)(smem + SPK_REGION);          // overlay, pre-loop
    float* Ibuf  = (float*)(smem + SPK_REGION + 16384);
    float* SSbuf = (float*)(smem + SPK_REGION + 32768);

    int p    = threadIdx.x;
    int h    = p >> 9;          // stream half: 0 or 1
    int q    = p & 511;         // column slot
    int blk  = blockIdx.x;
    int r0   = blk * R_PB;
    int wg   = q >> 6;
    int lane = q & 63;
    int n    = (int)ws[(WS_PERM >> 2) + q];
    int cw   = (int)ws[(WS_CNTW >> 2) + wg];     // wave-uniform
    int nit  = cw >> 4;                          // 8-entry chunks per half (<=6)
    const char* ip0 = (const char*)ws + WS_IDX + ws[(WS_IBASE >> 2) + wg]
                    + h * 1024 + lane * 16;
    const char* wp0 = (const char*)ws + WS_WT  + ws[(WS_WBASE >> 2) + wg]
                    + h * 2048 + lane * 32;
    int spk_n = SPK_OFF(n);                      // this column's record

    // stage this block's 8 rate rows (2048 floats = 512 float4)
    if (p < 512)
        ((float4*)rl)[p] = ((const float4*)(rates + (size_t)r0 * D_IN))[p];
    __syncthreads();

    float c0v[R_PB], v0v[R_PB];
    if (h == 0) {
        // input current I[r] = rates[r,:] . inW[n,:] (constant across steps)
        float I[R_PB] = {0.f, 0.f, 0.f, 0.f, 0.f, 0.f, 0.f, 0.f};
        const float4* wrow = (const float4*)(inW + (size_t)n * D_IN);
        for (int d4 = 0; d4 < D_IN / 4; ++d4) {
            float4 wv = wrow[d4];
            #pragma unroll
            for (int r = 0; r < R_PB; ++r) {
                const float* rr = rl + r * D_IN + d4 * 4;   // LDS broadcast
                I[r] += wv.x * rr[0] + wv.y * rr[1] + wv.z * rr[2] + wv.w * rr[3];
            }
        }
        // state load + initial u8 spikes
        uint2 s0 = make_uint2(0u, 0u);
        #pragma unroll
        for (int r = 0; r < R_PB; ++r) {
            c0v[r] = cin[(size_t)(r0 + r) * N_NEU + n];
            v0v[r] = vin[(size_t)(r0 + r) * N_NEU + n];
            unsigned bit = (c0v[r] > 0.f) ? 1u : 0u;
            if (r < 4) s0.x |= bit << (r * 8);
            else       s0.y |= bit << ((r - 4) * 8);
        }
        __syncthreads();   // rl reads done before recx region reuse
        ((float4*)(Ibuf + (size_t)q * 8))[0] = make_float4(I[0], I[1], I[2], I[3]);
        ((float4*)(Ibuf + (size_t)q * 8))[1] = make_float4(I[4], I[5], I[6], I[7]);
        ((float4*)(SSbuf + (size_t)q * 8))[0] = make_float4(0.f, 0.f, 0.f, 0.f);
        ((float4*)(SSbuf + (size_t)q * 8))[1] = make_float4(0.f, 0.f, 0.f, 0.f);
        *(uint2*)(smem + spk_n) = s0;
    } else {
        __syncthreads();   // matching barrier
    }

    // preload index stream into registers (constant across all steps; nit<=6)
    uint4 xr0, xr1, xr2, xr3, xr4, xr5;
    const uint4 xz = make_uint4(0u, 0u, 0u, 0u);
    xr0 =             *(const uint4*)(ip0);
    xr1 = (1 < nit) ? *(const uint4*)(ip0 + 2048)  : xz;
    xr2 = (2 < nit) ? *(const uint4*)(ip0 + 4096)  : xz;
    xr3 = (3 < nit) ? *(const uint4*)(ip0 + 6144)  : xz;
    xr4 = (4 < nit) ? *(const uint4*)(ip0 + 8192)  : xz;
    xr5 = (5 < nit) ? *(const uint4*)(ip0 + 10240) : xz;

    const float AS   = (float)0.8187307530779818;   // exp(-1/5)
    const float OMAS = (float)(1.0 - 0.8187307530779818);
    const float AM   = (float)0.9512294245007140;   // exp(-1/20)
    const float OMAM = (float)(1.0 - 0.9512294245007140);

    int T = nsteps_p[0];
    __syncthreads();

    #pragma unroll 1
    for (int t = 0; t < T; ++t) {
        float rec0 = 0.f, rec1 = 0.f, rec2 = 0.f, rec3 = 0.f;
        float rec4 = 0.f, rec5 = 0.f, rec6 = 0.f, rec7 = 0.f;
        uint2 a0, a1, a2, a3, a4, a5, a6, a7;
        uint2 b0, b1, b2, b3, b4, b5, b6, b7;
        float4 waA, wbA, waB, wbB;

        // chunk 0: issue weights (L2, longest pole) then gathers (addrs in regs)
        LDW(waA, wbA, 0)
        GATH(a, xr0)
        // k=0: prefetch 1 -> B, consume A
        if (1 < nit) { LDW(waB, wbB, 1) GATH(b, xr1) }
        CONS(a, waA, wbA)
        if (1 < nit) {
            if (2 < nit) { LDW(waA, wbA, 2) GATH(a, xr2) }
            CONS(b, waB, wbB)
        }
        if (2 < nit) {
            if (3 < nit) { LDW(waB, wbB, 3) GATH(b, xr3) }
            CONS(a, waA, wbA)
        }
        if (3 < nit) {
            if (4 < nit) { LDW(waA, wbA, 4) GATH(a, xr4) }
            CONS(b, waB, wbB)
        }
        if (4 < nit) {
            if (5 < nit) { LDW(waB, wbB, 5) GATH(b, xr5) }
            CONS(a, waA, wbA)
        }
        if (5 < nit) {
            CONS(b, waB, wbB)
        }

        if (h == 1) {
            float* rx = recx + (size_t)q * 8;
            *(float4*)rx       = make_float4(rec0, rec1, rec2, rec3);
            *(float4*)(rx + 4) = make_float4(rec4, rec5, rec6, rec7);
        }
        __syncthreads();   // half-1 partials visible; all spike reads done

        if (h == 0) {
            const float* rx = recx + (size_t)q * 8;
            const float* Iv = Ibuf + (size_t)q * 8;
            float* ssp = SSbuf + (size_t)q * 8;
            float4 ss0 = ((const float4*)ssp)[0];
            float4 ss1 = ((const float4*)ssp)[1];
            float ssa[R_PB] = {ss0.x, ss0.y, ss0.z, ss0.w,
                               ss1.x, ss1.y, ss1.z, ss1.w};
            float rca[R_PB] = {rec0, rec1, rec2, rec3, rec4, rec5, rec6, rec7};
            uint2 ns = make_uint2(0u, 0u);
            #pragma unroll
            for (int r = 0; r < R_PB; ++r) {
                float rc = rca[r] + rx[r];
                c0v[r] = AS * c0v[r] + OMAS * (Iv[r] + rc);
                v0v[r] = AM * v0v[r] + OMAM * c0v[r];
                ssa[r] += (v0v[r] > 0.f) ? 1.f : 0.f;
                unsigned bit = (c0v[r] > 0.f) ? 1u : 0u;
                if (r < 4) ns.x |= bit << (r * 8);
                else       ns.y |= bit << ((r - 4) * 8);
            }
            ((float4*)ssp)[0] = make_float4(ssa[0], ssa[1], ssa[2], ssa[3]);
            ((float4*)ssp)[1] = make_float4(ssa[4], ssa[5], ssa[6], ssa[7]);
            *(uint2*)(smem + spk_n) = ns;
        }
        __syncthreads();   // new spikes + ssum visible
    }

    if (h == 0) {
        const float* ssp = SSbuf + (size_t)q * 8;
        float invT = 1.0f / (float)T;
        size_t BN = (size_t)B_ROWS * N_NEU;
        #pragma unroll
        for (int r = 0; r < R_PB; ++r) {
            size_t off = (size_t)(r0 + r) * N_NEU + n;
            out[off]          = ssp[r] * invT;    // readout
            out[BN + off]     = v0v[r];           // final v
            out[2 * BN + off] = c0v[r];           // final c
        }
    }
}

// ---------------------------------------------------------------- launch
extern "C" void kernel_launch(void* const* d_in, const int* in_sizes, int n_in,
                              void* d_out, int out_size, void* d_ws, size_t ws_size,
                              hipStream_t stream)
{
    const float* rates = (const float*)d_in[0];
    const float* inW   = (const float*)d_in[1];
    const float* W     = (const float*)d_in[2];
    const float* vin   = (const float*)d_in[3];
    const float* cin   = (const float*)d_in[4];
    const int*   nst   = (const int*)d_in[5];
    uint32_t* ws = (uint32_t*)d_ws;
    float* out = (float*)d_out;
    (void)in_sizes; (void)n_in; (void)out_size; (void)ws_size;

    // zero CNT (harness poisons d_ws to 0xAA before every call)
    hipMemsetAsync((char*)d_ws + WS_CNT, 0, 2048, stream);

    lsm_count<<<128, 256, 0, stream>>>(W, ws);
    lsm_sort<<<1, 512, 0, stream>>>(ws);
    lsm_fill<<<N_NEU, 64, 0, stream>>>(W, ws);
    lsm_main<<<NBLK, 1024, 0, stream>>>(rates, inW, vin, cin, nst, ws, out);
}

// Round 12
// 363.530 us; speedup vs baseline: 1.3864x; 1.3864x over previous
//
#include <hip/hip_runtime.h>
#include <stdint.h>

// LiquidStateMachine on MI355X — round 12.
// r9/r10/r11 post-mortem: at 1024 threads/block this toolchain pins VGPR
// to 64 under every attribute tried (launch_bounds 2nd arg behaves CUDA-
// style: min BLOCKS/CU; 4 blocks x 16 waves clamps -> 8 waves/EU -> 64
// regs) -> the r9 pipeline always spilled (WRITE_SIZE 53MB scratch).
// r12 escapes structurally: 512-thread blocks, 256 blocks = 1 block/CU,
// R_PB=8, __launch_bounds__(512,1) -> >=256 VGPR budget under either
// interpretation. No stream halving (thread owns its column's full
// stream, nit<=12 chunks of 8); indices preloaded ONCE into registers
// (also deletes their per-step L2 traffic); weights streamed 2-deep
// (pipeline: issue chunk k+1 weights while consuming chunk k; gather
// addresses come from registers). recx/Ibuf/SSbuf merge machinery gone.
// Static demand ~156 regs — slack under 256: spill question disappears.
// Spike records u8 x 8 rows @ 8k (b64 gathers). Weights EXACT fp32
// (r2: any rounding flips spikes); u8 spike 0/1 exact.
//
// d_ws layout (bytes):
//   0      PERM[512]  sorted-rank -> column
//   2048   RANK[512]  column -> sorted rank
//   4096   CNT[512]   nnz per column          (zeroed via hipMemsetAsync)
//   8192   CNTW[8]    per-group padded trip count (multiple of 8)
//   8256   IBASE[8]   per-group byte base into IDX region
//   8320   WBASE[8]   per-group byte base into WT region
//   16384  IDX        u16 spike-offset (8k):
//                     byte = ib + (j>>3)*1024 + lane*16 + (j&7)*2
//   81920  WT         f32 w: byte = wb + (j>>3)*2048 + lane*32 + (j&7)*4

#define N_NEU 512
#define B_ROWS 2048
#define D_IN 256
#define R_PB 8
#define NBLK (B_ROWS / R_PB)   // 256 blocks x 512 threads = 1 block/CU

#define WS_PERM    0
#define WS_RANK    2048
#define WS_CNT     4096
#define WS_CNTW    8192
#define WS_IBASE   8256
#define WS_WBASE   8320
#define WS_IDX     16384
#define WS_WT      81920

// spike record: 8 bytes (8 rows x u8 0/1) at natural offset 8k
#define SPK_OFF(k)  ((k) << 3)
#define SPK_REGION  4096       // 512 neurons x 8 B

// ---------------------------------------------------------------- prep A
__global__ __launch_bounds__(256) void lsm_count(
    const float* __restrict__ W, uint32_t* __restrict__ ws)
{
    int t  = threadIdx.x;
    int k0 = blockIdx.x * 4;
    int c0 = 0, c1 = 0;
    #pragma unroll
    for (int kk = 0; kk < 4; ++kk) {
        const float* row = W + (size_t)(k0 + kk) * N_NEU;
        c0 += (row[t]       != 0.0f) ? 1 : 0;
        c1 += (row[t + 256] != 0.0f) ? 1 : 0;
    }
    if (c0) atomicAdd(&ws[(WS_CNT >> 2) + t],       (uint32_t)c0);
    if (c1) atomicAdd(&ws[(WS_CNT >> 2) + t + 256], (uint32_t)c1);
}

// ---------------------------------------------------------------- prep B
__global__ __launch_bounds__(512) void lsm_sort(uint32_t* __restrict__ ws)
{
    __shared__ int hist[N_NEU + 1];
    __shared__ int csort[N_NEU];
    __shared__ int gcw[8];

    int t = threadIdx.x;
    int creal = (int)ws[(WS_CNT >> 2) + t];
    for (int i = t; i < N_NEU + 1; i += 512) hist[i] = 0;
    __syncthreads();
    atomicAdd(&hist[creal], 1);
    __syncthreads();
    if (t == 0) {
        int acc = 0;
        for (int v = 0; v <= N_NEU; ++v) { int h = hist[v]; hist[v] = acc; acc += h; }
    }
    __syncthreads();
    int rank = atomicAdd(&hist[creal], 1);
    ws[(WS_PERM >> 2) + rank] = (uint32_t)t;
    ws[(WS_RANK >> 2) + t]    = (uint32_t)rank;
    csort[rank] = creal;
    __syncthreads();
    if (t < 8) {
        int cw = csort[t * 64 + 63];         // ascending -> group max is last
        cw = (cw + 7) & ~7;                  // pad to multiple of 8 (one chunk)
        gcw[t] = cw;
        ws[(WS_CNTW >> 2) + t] = (uint32_t)cw;
    }
    __syncthreads();
    if (t == 0) {
        int ai = 0, aw = 0;
        for (int g = 0; g < 8; ++g) {
            ws[(WS_IBASE >> 2) + g] = (uint32_t)ai;
            ws[(WS_WBASE >> 2) + g] = (uint32_t)aw;
            ai += gcw[g] * 64 * 2;           // bytes (u16 per entry)
            aw += gcw[g] * 64 * 4;           // bytes (f32 per entry)
        }
    }
    __syncthreads();
    // pad tail slots of this thread's column (offset 0 -> neuron 0, w=0)
    int wg = rank >> 6, ls = rank & 63;
    int cw = gcw[wg];
    uint32_t ib = ws[(WS_IBASE >> 2) + wg];
    uint32_t wb = ws[(WS_WBASE >> 2) + wg];
    char* base = (char*)ws;
    for (int j = creal; j < cw; ++j) {
        *(unsigned short*)(base + WS_IDX + ib + (j >> 3) * 1024 + ls * 16 + (j & 7) * 2) = 0;
        *(float*)(base + WS_WT + wb + (j >> 3) * 2048 + ls * 32 + (j & 7) * 4) = 0.0f;
    }
}

// ---------------------------------------------------------------- prep C
__global__ __launch_bounds__(64) void lsm_fill(
    const float* __restrict__ W, uint32_t* __restrict__ ws)
{
    int c    = blockIdx.x;
    int lane = threadIdx.x;
    char* base = (char*)ws;
    uint32_t rank = ws[(WS_RANK >> 2) + c];
    int wg = (int)(rank >> 6), ls = (int)(rank & 63);
    uint32_t ib = ws[(WS_IBASE >> 2) + wg];
    uint32_t wb = ws[(WS_WBASE >> 2) + wg];

    __shared__ int ctr;
    if (lane == 0) ctr = 0;
    __syncthreads();

    for (int k = lane; k < N_NEU; k += 64) {
        float wv = W[(size_t)k * N_NEU + c];
        if (wv != 0.0f) {
            int j = atomicAdd(&ctr, 1);      // order within column irrelevant
            *(unsigned short*)(base + WS_IDX + ib + (j >> 3) * 1024 + ls * 16 + (j & 7) * 2)
                = (unsigned short)SPK_OFF(k);
            *(float*)(base + WS_WT + wb + (j >> 3) * 2048 + ls * 32 + (j & 7) * 4) = wv;
        }
    }
}

// -------- spill-proof pipeline macros (all scalars, no arrays/fns) --------
#define GATH(P, X) \
    P##0 = *(const uint2*)(smem + ((X).x & 0xffffu)); \
    P##1 = *(const uint2*)(smem + ((X).x >> 16));     \
    P##2 = *(const uint2*)(smem + ((X).y & 0xffffu)); \
    P##3 = *(const uint2*)(smem + ((X).y >> 16));     \
    P##4 = *(const uint2*)(smem + ((X).z & 0xffffu)); \
    P##5 = *(const uint2*)(smem + ((X).z >> 16));     \
    P##6 = *(const uint2*)(smem + ((X).w & 0xffffu)); \
    P##7 = *(const uint2*)(smem + ((X).w >> 16));

// one entry: weight W times 8 rows' u8 spikes ((dw>>8j)&0xff -> v_cvt_f32_ubyteN)
#define C1(S, W) \
    rec0 = fmaf((W), (float)((S).x & 0xffu),         rec0); \
    rec1 = fmaf((W), (float)(((S).x >> 8) & 0xffu),  rec1); \
    rec2 = fmaf((W), (float)(((S).x >> 16) & 0xffu), rec2); \
    rec3 = fmaf((W), (float)((S).x >> 24),           rec3); \
    rec4 = fmaf((W), (float)((S).y & 0xffu),         rec4); \
    rec5 = fmaf((W), (float)(((S).y >> 8) & 0xffu),  rec5); \
    rec6 = fmaf((W), (float)(((S).y >> 16) & 0xffu), rec6); \
    rec7 = fmaf((W), (float)((S).y >> 24),           rec7);

#define CONS(P, WA, WB) \
    C1(P##0, (WA).x) C1(P##1, (WA).y) C1(P##2, (WA).z) C1(P##3, (WA).w) \
    C1(P##4, (WB).x) C1(P##5, (WB).y) C1(P##6, (WB).z) C1(P##7, (WB).w)

#define LDW(WA, WB, K) \
    WA = ((const float4*)(wp0 + (K) * 2048))[0]; \
    WB = ((const float4*)(wp0 + (K) * 2048))[1];

// ---------------------------------------------------------------- main
// LDS map:
//   [0,4096)       spk : u8 [8 rows] per neuron, 8 B records at 8k
//                  (at offset 0 so gather addr == precomputed stream value)
//   [4096,12288)   rl  : rates staging [8][256] f32 (pre-loop only)
__global__ __launch_bounds__(512, 1)   // >=256 VGPR budget either way
void lsm_main(
    const float* __restrict__ rates, const float* __restrict__ inW,
    const float* __restrict__ vin,   const float* __restrict__ cin,
    const int* __restrict__ nsteps_p,
    const uint32_t* __restrict__ ws, float* __restrict__ out)
{
    __shared__ __align__(16) unsigned char smem[SPK_REGION + 8192];
    float* rl = (float*)(smem + SPK_REGION);

    int q    = threadIdx.x;     // column slot (== thread id)
    int blk  = blockIdx.x;
    int r0   = blk * R_PB;
    int wg   = q >> 6;
    int lane = q & 63;
    int n    = (int)ws[(WS_PERM >> 2) + q];
    int cw   = (int)ws[(WS_CNTW >> 2) + wg];     // wave-uniform
    int nit  = cw >> 3;                          // 8-entry chunks (<=12)
    const char* ip0 = (const char*)ws + WS_IDX + ws[(WS_IBASE >> 2) + wg]
                    + lane * 16;
    const char* wp0 = (const char*)ws + WS_WT  + ws[(WS_WBASE >> 2) + wg]
                    + lane * 32;
    int spk_n = SPK_OFF(n);                      // this column's record

    // stage this block's 8 rate rows (2048 floats = 512 float4)
    ((float4*)rl)[q] = ((const float4*)(rates + (size_t)r0 * D_IN))[q];
    __syncthreads();

    // input current I[r] = rates[r,:] . inW[n,:] (constant across steps)
    float I[R_PB] = {0.f, 0.f, 0.f, 0.f, 0.f, 0.f, 0.f, 0.f};
    {
        const float4* wrow = (const float4*)(inW + (size_t)n * D_IN);
        for (int d4 = 0; d4 < D_IN / 4; ++d4) {
            float4 wv = wrow[d4];
            #pragma unroll
            for (int r = 0; r < R_PB; ++r) {
                const float* rr = rl + r * D_IN + d4 * 4;   // LDS broadcast
                I[r] += wv.x * rr[0] + wv.y * rr[1] + wv.z * rr[2] + wv.w * rr[3];
            }
        }
    }

    // state load + initial u8 spikes
    float c0v[R_PB], v0v[R_PB], ssum[R_PB];
    uint2 sini = make_uint2(0u, 0u);
    #pragma unroll
    for (int r = 0; r < R_PB; ++r) {
        c0v[r] = cin[(size_t)(r0 + r) * N_NEU + n];
        v0v[r] = vin[(size_t)(r0 + r) * N_NEU + n];
        ssum[r] = 0.f;
        unsigned bit = (c0v[r] > 0.f) ? 1u : 0u;
        if (r < 4) sini.x |= bit << (r * 8);
        else       sini.y |= bit << ((r - 4) * 8);
    }
    *(uint2*)(smem + spk_n) = sini;

    // preload ENTIRE index stream into registers (constant across steps)
    uint4 xr0, xr1, xr2, xr3, xr4, xr5, xr6, xr7, xr8, xr9, xr10, xr11;
    const uint4 xz = make_uint4(0u, 0u, 0u, 0u);
    xr0  =              *(const uint4*)(ip0);
    xr1  = (1  < nit) ? *(const uint4*)(ip0 + 1024)  : xz;
    xr2  = (2  < nit) ? *(const uint4*)(ip0 + 2048)  : xz;
    xr3  = (3  < nit) ? *(const uint4*)(ip0 + 3072)  : xz;
    xr4  = (4  < nit) ? *(const uint4*)(ip0 + 4096)  : xz;
    xr5  = (5  < nit) ? *(const uint4*)(ip0 + 5120)  : xz;
    xr6  = (6  < nit) ? *(const uint4*)(ip0 + 6144)  : xz;
    xr7  = (7  < nit) ? *(const uint4*)(ip0 + 7168)  : xz;
    xr8  = (8  < nit) ? *(const uint4*)(ip0 + 8192)  : xz;
    xr9  = (9  < nit) ? *(const uint4*)(ip0 + 9216)  : xz;
    xr10 = (10 < nit) ? *(const uint4*)(ip0 + 10240) : xz;
    xr11 = (11 < nit) ? *(const uint4*)(ip0 + 11264) : xz;

    const float AS   = (float)0.8187307530779818;   // exp(-1/5)
    const float OMAS = (float)(1.0 - 0.8187307530779818);
    const float AM   = (float)0.9512294245007140;   // exp(-1/20)
    const float OMAM = (float)(1.0 - 0.9512294245007140);

    int T = nsteps_p[0];
    __syncthreads();   // initial spikes visible

    #pragma unroll 1
    for (int t = 0; t < T; ++t) {
        float rec0 = 0.f, rec1 = 0.f, rec2 = 0.f, rec3 = 0.f;
        float rec4 = 0.f, rec5 = 0.f, rec6 = 0.f, rec7 = 0.f;
        uint2 a0, a1, a2, a3, a4, a5, a6, a7;
        uint2 b0, b1, b2, b3, b4, b5, b6, b7;
        float4 waA, wbA, waB, wbB;

        // 2-stage pipeline: gathers address from registers, weights 2-deep
        LDW(waA, wbA, 0)
        GATH(a, xr0)
        if (1 < nit)  { LDW(waB, wbB, 1)  GATH(b, xr1)  }
        CONS(a, waA, wbA)
        if (1 < nit)  {
            if (2 < nit)  { LDW(waA, wbA, 2)  GATH(a, xr2)  }
            CONS(b, waB, wbB)
        }
        if (2 < nit)  {
            if (3 < nit)  { LDW(waB, wbB, 3)  GATH(b, xr3)  }
            CONS(a, waA, wbA)
        }
        if (3 < nit)  {
            if (4 < nit)  { LDW(waA, wbA, 4)  GATH(a, xr4)  }
            CONS(b, waB, wbB)
        }
        if (4 < nit)  {
            if (5 < nit)  { LDW(waB, wbB, 5)  GATH(b, xr5)  }
            CONS(a, waA, wbA)
        }
        if (5 < nit)  {
            if (6 < nit)  { LDW(waA, wbA, 6)  GATH(a, xr6)  }
            CONS(b, waB, wbB)
        }
        if (6 < nit)  {
            if (7 < nit)  { LDW(waB, wbB, 7)  GATH(b, xr7)  }
            CONS(a, waA, wbA)
        }
        if (7 < nit)  {
            if (8 < nit)  { LDW(waA, wbA, 8)  GATH(a, xr8)  }
            CONS(b, waB, wbB)
        }
        if (8 < nit)  {
            if (9 < nit)  { LDW(waB, wbB, 9)  GATH(b, xr9)  }
            CONS(a, waA, wbA)
        }
        if (9 < nit)  {
            if (10 < nit) { LDW(waA, wbA, 10) GATH(a, xr10) }
            CONS(b, waB, wbB)
        }
        if (10 < nit) {
            if (11 < nit) { LDW(waB, wbB, 11) GATH(b, xr11) }
            CONS(a, waA, wbA)
        }
        if (11 < nit) {
            CONS(b, waB, wbB)
        }

        __syncthreads();   // all spike reads for this step done

        uint2 ns = make_uint2(0u, 0u);
        {
            float rca[R_PB] = {rec0, rec1, rec2, rec3, rec4, rec5, rec6, rec7};
            #pragma unroll
            for (int r = 0; r < R_PB; ++r) {
                c0v[r] = AS * c0v[r] + OMAS * (I[r] + rca[r]);
                v0v[r] = AM * v0v[r] + OMAM * c0v[r];
                ssum[r] += (v0v[r] > 0.f) ? 1.f : 0.f;
                unsigned bit = (c0v[r] > 0.f) ? 1u : 0u;
                if (r < 4) ns.x |= bit << (r * 8);
                else       ns.y |= bit << ((r - 4) * 8);
            }
        }
        *(uint2*)(smem + spk_n) = ns;
        __syncthreads();   // new spikes visible
    }

    float invT = 1.0f / (float)T;
    size_t BN = (size_t)B_ROWS * N_NEU;
    #pragma unroll
    for (int r = 0; r < R_PB; ++r) {
        size_t off = (size_t)(r0 + r) * N_NEU + n;
        out[off]          = ssum[r] * invT;   // readout
        out[BN + off]     = v0v[r];           // final v
        out[2 * BN + off] = c0v[r];           // final c
    }
}

// ---------------------------------------------------------------- launch
extern "C" void kernel_launch(void* const* d_in, const int* in_sizes, int n_in,
                              void* d_out, int out_size, void* d_ws, size_t ws_size,
                              hipStream_t stream)
{
    const float* rates = (const float*)d_in[0];
    const float* inW   = (const float*)d_in[1];
    const float* W     = (const float*)d_in[2];
    const float* vin   = (const float*)d_in[3];
    const float* cin   = (const float*)d_in[4];
    const int*   nst   = (const int*)d_in[5];
    uint32_t* ws = (uint32_t*)d_ws;
    float* out = (float*)d_out;
    (void)in_sizes; (void)n_in; (void)out_size; (void)ws_size;

    // zero CNT (harness poisons d_ws to 0xAA before every call)
    hipMemsetAsync((char*)d_ws + WS_CNT, 0, 2048, stream);

    lsm_count<<<128, 256, 0, stream>>>(W, ws);
    lsm_sort<<<1, 512, 0, stream>>>(ws);
    lsm_fill<<<N_NEU, 64, 0, stream>>>(W, ws);
    lsm_main<<<NBLK, 512, 0, stream>>>(rates, inW, vin, cin, nst, ws, out);
}